// Round 2
// baseline (1323.818 us; speedup 1.0000x reference)
//
#include <hip/hip_runtime.h>
#include <hip/hip_bf16.h>

#define B_ 4
#define S_ 2048
#define D_ 768
#define H_ 12
#define HD 64

__device__ __forceinline__ float fmapf(float x) { return x > 0.f ? x + 1.f : __expf(x); }

// ---------------------------------------------------------------------------
// Kernel 1: qkv = x @ qkv_w.T ; write fmap(q), fmap(k), v in (B,H,S,hd) fp32
// M=8192 (B*S), K=768, N=2304 (3*H*hd). 64x64 tile, BK=16, 256 thr, 4x4/thr.
// ---------------------------------------------------------------------------
__global__ __launch_bounds__(256) void qkv_gemm(const float* __restrict__ x,
                                                const float* __restrict__ w,
                                                float* __restrict__ qf,
                                                float* __restrict__ kf,
                                                float* __restrict__ vv) {
    __shared__ float As[16][64];
    __shared__ float Bs[16][64];
    const int K = 768;
    int n0 = blockIdx.x * 64, m0 = blockIdx.y * 64;
    int tid = threadIdx.x;
    int tx = tid & 15, ty = tid >> 4;
    float acc[4][4] = {};
    for (int k0 = 0; k0 < K; k0 += 16) {
        int lin = tid * 4;
        int mA = lin >> 4, kA = lin & 15;  // 4 consecutive k per thread
        const float* xp = x + (size_t)(m0 + mA) * K + k0 + kA;
        const float* wp = w + (size_t)(n0 + mA) * K + k0 + kA;
        float4 xa = *(const float4*)xp;
        float4 wa = *(const float4*)wp;
        As[kA + 0][mA] = xa.x; As[kA + 1][mA] = xa.y;
        As[kA + 2][mA] = xa.z; As[kA + 3][mA] = xa.w;
        Bs[kA + 0][mA] = wa.x; Bs[kA + 1][mA] = wa.y;
        Bs[kA + 2][mA] = wa.z; Bs[kA + 3][mA] = wa.w;
        __syncthreads();
#pragma unroll
        for (int kk = 0; kk < 16; kk++) {
            float a_[4], b_[4];
#pragma unroll
            for (int i = 0; i < 4; i++) a_[i] = As[kk][ty * 4 + i];
#pragma unroll
            for (int j = 0; j < 4; j++) b_[j] = Bs[kk][tx * 4 + j];
#pragma unroll
            for (int i = 0; i < 4; i++)
#pragma unroll
                for (int j = 0; j < 4; j++) acc[i][j] += a_[i] * b_[j];
        }
        __syncthreads();
    }
#pragma unroll
    for (int i = 0; i < 4; i++) {
        int m = m0 + ty * 4 + i;
        int b = m >> 11, s = m & 2047;
#pragma unroll
        for (int j = 0; j < 4; j++) {
            int n = n0 + tx * 4 + j;
            int t3 = n / 768;
            int r = n - t3 * 768;
            int h = r >> 6, d = r & 63;
            size_t dst = (((size_t)(b * H_ + h) * S_) + s) * HD + d;
            float val = acc[i][j];
            if (t3 == 0)
                qf[dst] = fmapf(val);
            else if (t3 == 1)
                kf[dst] = fmapf(val);
            else
                vv[dst] = val;
        }
    }
}

// ---------------------------------------------------------------------------
// Kernel 2: per (b,h): kv_stride (64x64), ksum_stride (64), and anchor_out
// (12x64) for the global band (needs full-S kv + ksum).
// 48 blocks x 256 threads. Thread t: d = t>>2 (row), e-group = t&3 (16 cols).
// ---------------------------------------------------------------------------
__global__ __launch_bounds__(256) void band_precompute(const float* __restrict__ kf,
                                                       const float* __restrict__ vv,
                                                       const float* __restrict__ aq,
                                                       float* __restrict__ kvs,
                                                       float* __restrict__ ksums,
                                                       float* __restrict__ aout) {
    int bh = blockIdx.x;
    int h = bh % H_;
    const float* kfp = kf + (size_t)bh * S_ * HD;
    const float* vp = vv + (size_t)bh * S_ * HD;
    __shared__ float kt[16][64];
    __shared__ float vt[16][64];
    __shared__ float kvg[64][64];
    __shared__ float ksgL[64];
    __shared__ float anorm[12];
    int tid = threadIdx.x;
    int d = tid >> 2, eg = tid & 3, e0 = eg * 16;
    float accg[16], accs[16];
#pragma unroll
    for (int i = 0; i < 16; i++) { accg[i] = 0.f; accs[i] = 0.f; }
    float ksg = 0.f, kss = 0.f;
    for (int s0 = 0; s0 < S_; s0 += 16) {
        for (int i = tid; i < 1024; i += 256) {
            kt[i >> 6][i & 63] = kfp[(size_t)s0 * HD + i];
            vt[i >> 6][i & 63] = vp[(size_t)s0 * HD + i];
        }
        __syncthreads();
#pragma unroll 4
        for (int ss = 0; ss < 16; ss++) {
            float kd = kt[ss][d];
            bool str = ((s0 + ss) % 3) == 0;  // block-uniform
            ksg += kd;
            if (str) kss += kd;
#pragma unroll
            for (int i = 0; i < 16; i++) {
                float ve = vt[ss][e0 + i];
                accg[i] += kd * ve;
                if (str) accs[i] += kd * ve;
            }
        }
        __syncthreads();
    }
    float* kvsp = kvs + (size_t)bh * 4096;
#pragma unroll
    for (int i = 0; i < 16; i++) kvsp[d * 64 + e0 + i] = accs[i];
    if (eg == 0) ksums[bh * 64 + d] = kss;
#pragma unroll
    for (int i = 0; i < 16; i++) kvg[d][e0 + i] = accg[i];
    if (eg == 0) ksgL[d] = ksg;
    __syncthreads();
    if (tid < 12) {
        float nrm = 0.f;
        for (int dd = 0; dd < 64; dd++)
            nrm += fmapf(aq[h * 768 + tid * 64 + dd]) * ksgL[dd];
        anorm[tid] = fmaxf(nrm, 1e-6f);
    }
    __syncthreads();
    for (int r = tid; r < 768; r += 256) {
        int a = r >> 6, e = r & 63;
        float acc = 0.f;
        for (int dd = 0; dd < 64; dd++)
            acc += fmapf(aq[h * 768 + a * 64 + dd]) * kvg[dd][e];
        aout[(size_t)bh * 768 + r] = acc / anorm[a];
    }
}

// ---------------------------------------------------------------------------
// Kernel 3: per 64-token tile of one (b,h): local band (window 12; padded
// keys = fmap(0)=1, padded v = 0), stride band (q @ kv_s / q.ksum_s),
// global band (q.aq_f -> weighted anchor_out). Combine with softmax weights,
// write attn in (B,S,768) layout for the final GEMM.
// Grid: (B*H)*32 blocks of 256 threads.  LDS ~63 KB.
// ---------------------------------------------------------------------------
__global__ __launch_bounds__(256) void combine(const float* __restrict__ qf,
                                               const float* __restrict__ kf,
                                               const float* __restrict__ vv,
                                               const float* __restrict__ aq,
                                               const float* __restrict__ kvs,
                                               const float* __restrict__ ksums,
                                               const float* __restrict__ aout,
                                               const float* __restrict__ wlp,
                                               const float* __restrict__ wsp,
                                               const float* __restrict__ wgp,
                                               float* __restrict__ attn) {
    __shared__ float kvsL[64][65];
    __shared__ float qft[64][65];
    __shared__ float kft[75][65];
    __shared__ float aoutL[12][64];
    __shared__ float qkl[64][12];
    __shared__ float qkg[64][12];
    __shared__ float ksumL[64];
    __shared__ float nl[64], ng[64], ns[64];
    int bh = blockIdx.x >> 5, stile = blockIdx.x & 31;
    int b = bh / H_, h = bh % H_;
    int s0 = stile * 64;
    int tid = threadIdx.x;
    const float* qfp = qf + (size_t)bh * S_ * HD;
    const float* kfp = kf + (size_t)bh * S_ * HD;
    const float* vp = vv + (size_t)bh * S_ * HD;
    // softmax of the three scalar weights (redundant per thread, cheap)
    float a0 = wlp[0], a1 = wsp[0], a2 = wgp[0];
    float mx = fmaxf(a0, fmaxf(a1, a2));
    float ew0 = __expf(a0 - mx), ew1 = __expf(a1 - mx), ew2 = __expf(a2 - mx);
    float inv = 1.f / (ew0 + ew1 + ew2);
    float wl = ew0 * inv, wsb = ew1 * inv, wg = ew2 * inv;
    // stage
    for (int i = tid; i < 4096; i += 256) {
        kvsL[i >> 6][i & 63] = kvs[(size_t)bh * 4096 + i];
        qft[i >> 6][i & 63] = qfp[(size_t)s0 * HD + i];
    }
    for (int i = tid; i < 75 * 64; i += 256) {
        int row = i >> 6, c = i & 63;
        int gs = s0 + row - 6;
        kft[row][c] = (gs >= 0 && gs < S_) ? kfp[(size_t)gs * HD + c] : 1.0f;
    }
    if (tid < 64) ksumL[tid] = ksums[bh * 64 + tid];
    for (int i = tid; i < 768; i += 256) aoutL[i >> 6][i & 63] = aout[(size_t)bh * 768 + i];
    __syncthreads();
    // phase A: 64 tokens x (12 local qk + 12 global qk + 1 stride norm)
    for (int r = tid; r < 64 * 25; r += 256) {
        int token = r / 25;
        int which = r - token * 25;
        float acc = 0.f;
        if (which < 12) {
            int row = token + which;
#pragma unroll 8
            for (int dd = 0; dd < 64; dd++) acc += qft[token][dd] * kft[row][dd];
            qkl[token][which] = acc;
        } else if (which < 24) {
            int a = which - 12;
            const float* ap = aq + h * 768 + a * 64;
#pragma unroll 8
            for (int dd = 0; dd < 64; dd++) acc += qft[token][dd] * fmapf(ap[dd]);
            qkg[token][a] = acc;
        } else {
#pragma unroll 8
            for (int dd = 0; dd < 64; dd++) acc += qft[token][dd] * ksumL[dd];
            ns[token] = acc;
        }
    }
    __syncthreads();
    if (tid < 64) {
        float sl = 0.f, sg = 0.f;
#pragma unroll
        for (int j = 0; j < 12; j++) { sl += qkl[tid][j]; sg += qkg[tid][j]; }
        nl[tid] = fmaxf(sl, 1e-6f);
        ng[tid] = fmaxf(sg, 1e-6f);
        ns[tid] = fmaxf(ns[tid], 1e-6f);
    }
    __syncthreads();
    // phase B: each (token,e) output
    int e = tid & 63, tg = tid >> 6;
    for (int token = tg; token < 64; token += 4) {
        float ol = 0.f;
#pragma unroll
        for (int j = 0; j < 12; j++) {
            int gs = s0 + token + j - 6;  // uniform per wave
            float vval = (gs >= 0 && gs < S_) ? vp[(size_t)gs * HD + e] : 0.f;
            ol += qkl[token][j] * vval;
        }
        float os = 0.f;
#pragma unroll 16
        for (int dd = 0; dd < 64; dd++) os += qft[token][dd] * kvsL[dd][e];
        float og = 0.f;
#pragma unroll
        for (int a = 0; a < 12; a++) og += qkg[token][a] * aoutL[a][e];
        float res = wl * ol / nl[token] + wsb * os / ns[token] + wg * og / ng[token];
        attn[((size_t)(b * S_ + s0 + token)) * 768 + h * 64 + e] = res;
    }
}

// ---------------------------------------------------------------------------
// Kernel 4: out = attn @ out_w.T  (8192x768)@(768x768) -> fp32
// ---------------------------------------------------------------------------
__global__ __launch_bounds__(256) void out_gemm(const float* __restrict__ attn,
                                                const float* __restrict__ w,
                                                float* __restrict__ out) {
    __shared__ float As[16][64];
    __shared__ float Bs[16][64];
    const int K = 768;
    int n0 = blockIdx.x * 64, m0 = blockIdx.y * 64;
    int tid = threadIdx.x;
    int tx = tid & 15, ty = tid >> 4;
    float acc[4][4] = {};
    for (int k0 = 0; k0 < K; k0 += 16) {
        int lin = tid * 4;
        int mA = lin >> 4, kA = lin & 15;
        const float* ap = attn + (size_t)(m0 + mA) * K + k0 + kA;
        const float* wp = w + (size_t)(n0 + mA) * K + k0 + kA;
        float4 xa = *(const float4*)ap;
        float4 wa = *(const float4*)wp;
        As[kA + 0][mA] = xa.x; As[kA + 1][mA] = xa.y;
        As[kA + 2][mA] = xa.z; As[kA + 3][mA] = xa.w;
        Bs[kA + 0][mA] = wa.x; Bs[kA + 1][mA] = wa.y;
        Bs[kA + 2][mA] = wa.z; Bs[kA + 3][mA] = wa.w;
        __syncthreads();
#pragma unroll
        for (int kk = 0; kk < 16; kk++) {
            float a_[4], b_[4];
#pragma unroll
            for (int i = 0; i < 4; i++) a_[i] = As[kk][ty * 4 + i];
#pragma unroll
            for (int j = 0; j < 4; j++) b_[j] = Bs[kk][tx * 4 + j];
#pragma unroll
            for (int i = 0; i < 4; i++)
#pragma unroll
                for (int j = 0; j < 4; j++) acc[i][j] += a_[i] * b_[j];
        }
        __syncthreads();
    }
#pragma unroll
    for (int i = 0; i < 4; i++) {
        int m = m0 + ty * 4 + i;
#pragma unroll
        for (int j = 0; j < 4; j++) {
            int n = n0 + tx * 4 + j;
            out[(size_t)m * 768 + n] = acc[i][j];
        }
    }
}

extern "C" void kernel_launch(void* const* d_in, const int* in_sizes, int n_in,
                              void* d_out, int out_size, void* d_ws, size_t ws_size,
                              hipStream_t stream) {
    const float* x = (const float*)d_in[0];
    const float* qkvw = (const float*)d_in[1];
    const float* outw = (const float*)d_in[2];
    const float* aq = (const float*)d_in[3];
    const float* wlp = (const float*)d_in[4];
    const float* wsp = (const float*)d_in[5];
    const float* wgp = (const float*)d_in[6];

    float* ws = (float*)d_ws;
    const size_t NBH = (size_t)B_ * H_ * S_ * HD;  // 6,291,456
    float* qf = ws;
    float* kf = qf + NBH;
    float* vv = kf + NBH;
    float* attn = vv + NBH;
    float* kvs = attn + NBH;             // 48*4096
    float* ksums = kvs + 48 * 4096;      // 48*64
    float* aout = ksums + 48 * 64;       // 48*768

    qkv_gemm<<<dim3(36, 128), 256, 0, stream>>>(x, qkvw, qf, kf, vv);
    band_precompute<<<48, 256, 0, stream>>>(kf, vv, aq, kvs, ksums, aout);
    combine<<<48 * 32, 256, 0, stream>>>(qf, kf, vv, aq, kvs, ksums, aout, wlp, wsp, wgp, attn);
    out_gemm<<<dim3(12, 128), 256, 0, stream>>>(attn, outw, (float*)d_out);
}

// Round 5
// 856.420 us; speedup vs baseline: 1.5458x; 1.5458x over previous
//
#include <hip/hip_runtime.h>
#include <hip/hip_bf16.h>

#define B_ 4
#define S_ 2048
#define D_ 768
#define H_ 12
#define HD 64

__device__ __forceinline__ float fmapf(float x) { return x > 0.f ? x + 1.f : __expf(x); }

// ---------------------------------------------------------------------------
// Kernel 1: qkv = x @ qkv_w.T ; write fmap(q), fmap(k), v in (B,H,S,hd) fp32
// M=8192 (B*S), K=768, N=2304 (3*H*hd). 64x64 tile, BK=16, 256 thr, 4x4/thr.
// ---------------------------------------------------------------------------
__global__ __launch_bounds__(256) void qkv_gemm(const float* __restrict__ x,
                                                const float* __restrict__ w,
                                                float* __restrict__ qf,
                                                float* __restrict__ kf,
                                                float* __restrict__ vv) {
    __shared__ float As[16][64];
    __shared__ float Bs[16][64];
    const int K = 768;
    int n0 = blockIdx.x * 64, m0 = blockIdx.y * 64;
    int tid = threadIdx.x;
    int tx = tid & 15, ty = tid >> 4;
    float acc[4][4] = {};
    for (int k0 = 0; k0 < K; k0 += 16) {
        int lin = tid * 4;
        int mA = lin >> 4, kA = lin & 15;  // 4 consecutive k per thread
        const float* xp = x + (size_t)(m0 + mA) * K + k0 + kA;
        const float* wp = w + (size_t)(n0 + mA) * K + k0 + kA;
        float4 xa = *(const float4*)xp;
        float4 wa = *(const float4*)wp;
        As[kA + 0][mA] = xa.x; As[kA + 1][mA] = xa.y;
        As[kA + 2][mA] = xa.z; As[kA + 3][mA] = xa.w;
        Bs[kA + 0][mA] = wa.x; Bs[kA + 1][mA] = wa.y;
        Bs[kA + 2][mA] = wa.z; Bs[kA + 3][mA] = wa.w;
        __syncthreads();
#pragma unroll
        for (int kk = 0; kk < 16; kk++) {
            float a_[4], b_[4];
#pragma unroll
            for (int i = 0; i < 4; i++) a_[i] = As[kk][ty * 4 + i];
#pragma unroll
            for (int j = 0; j < 4; j++) b_[j] = Bs[kk][tx * 4 + j];
#pragma unroll
            for (int i = 0; i < 4; i++)
#pragma unroll
                for (int j = 0; j < 4; j++) acc[i][j] += a_[i] * b_[j];
        }
        __syncthreads();
    }
#pragma unroll
    for (int i = 0; i < 4; i++) {
        int m = m0 + ty * 4 + i;
        int b = m >> 11, s = m & 2047;
#pragma unroll
        for (int j = 0; j < 4; j++) {
            int n = n0 + tx * 4 + j;
            int t3 = n / 768;
            int r = n - t3 * 768;
            int h = r >> 6, d = r & 63;
            size_t dst = (((size_t)(b * H_ + h) * S_) + s) * HD + d;
            float val = acc[i][j];
            if (t3 == 0)
                qf[dst] = fmapf(val);
            else if (t3 == 1)
                kf[dst] = fmapf(val);
            else
                vv[dst] = val;
        }
    }
}

// ---------------------------------------------------------------------------
// Kernel 2a: partial kv states. Grid = 48 bh * 8 chunks (256 tokens each).
// Each block: partial kv_global + kv_stride (64x64 each) and partial
// ksum_global/stride (64 each) for its chunk.
// pkv layout: ((bh*8 + c)*2 + {0=global,1=stride})*4096, d*64 + e.
// pks layout: (bh*8 + c)*128 + {0:64 global, 64:128 stride}.
// Both live INSIDE the attn workspace region (dead until `combine`).
// ---------------------------------------------------------------------------
__global__ __launch_bounds__(256) void band_partial(const float* __restrict__ kf,
                                                    const float* __restrict__ vv,
                                                    float* __restrict__ pkv,
                                                    float* __restrict__ pks) {
    int bh = blockIdx.x >> 3, chunk = blockIdx.x & 7;
    int sbase = chunk * 256;
    const float* kfp = kf + (size_t)bh * S_ * HD + (size_t)sbase * HD;
    const float* vp = vv + (size_t)bh * S_ * HD + (size_t)sbase * HD;
    __shared__ float kt[16][64];
    __shared__ float vt[16][64];
    int tid = threadIdx.x;
    int d = tid >> 2, eg = tid & 3, e0 = eg * 16;
    float accg[16], accs[16];
#pragma unroll
    for (int i = 0; i < 16; i++) { accg[i] = 0.f; accs[i] = 0.f; }
    float ksg = 0.f, kss = 0.f;
    for (int s0 = 0; s0 < 256; s0 += 16) {
        for (int i = tid; i < 1024; i += 256) {
            kt[i >> 6][i & 63] = kfp[(size_t)s0 * HD + i];
            vt[i >> 6][i & 63] = vp[(size_t)s0 * HD + i];
        }
        __syncthreads();
#pragma unroll 4
        for (int ss = 0; ss < 16; ss++) {
            float kd = kt[ss][d];
            bool str = ((sbase + s0 + ss) % 3) == 0;  // block-uniform
            ksg += kd;
            if (str) kss += kd;
#pragma unroll
            for (int i = 0; i < 16; i++) {
                float ve = vt[ss][e0 + i];
                accg[i] += kd * ve;
                if (str) accs[i] += kd * ve;
            }
        }
        __syncthreads();
    }
    float* pg = pkv + (size_t)blockIdx.x * 2 * 4096;
#pragma unroll
    for (int i = 0; i < 16; i++) pg[d * 64 + e0 + i] = accg[i];
#pragma unroll
    for (int i = 0; i < 16; i++) pg[4096 + d * 64 + e0 + i] = accs[i];
    if (eg == 0) {
        pks[blockIdx.x * 128 + d] = ksg;
        pks[blockIdx.x * 128 + 64 + d] = kss;
    }
}

// ---------------------------------------------------------------------------
// Kernel 2b: reduce partials + anchor outputs. Grid = 48 bh * 4 e-blocks
// (16 columns each). Writes kvs (stride kv), ksums (stride), aout.
// ---------------------------------------------------------------------------
__global__ __launch_bounds__(256) void band_reduce(const float* __restrict__ pkv,
                                                   const float* __restrict__ pks,
                                                   const float* __restrict__ aq,
                                                   float* __restrict__ kvs,
                                                   float* __restrict__ ksums,
                                                   float* __restrict__ aout) {
    int bh = blockIdx.x >> 2, eb = blockIdx.x & 3, e0 = eb * 16;
    int h = bh % H_;
    __shared__ float kvgL[64][17];
    __shared__ float ksgL[64];
    __shared__ float anorm[12];
    int tid = threadIdx.x;
    for (int idx = tid; idx < 1024; idx += 256) {
        int d = idx >> 4, j = idx & 15;
        float sg = 0.f, ss = 0.f;
        const float* p = pkv + (size_t)(bh * 8) * 2 * 4096 + d * 64 + e0 + j;
#pragma unroll 4
        for (int c = 0; c < 8; c++) {
            sg += p[0];
            ss += p[4096];
            p += 2 * 4096;
        }
        kvgL[d][j] = sg;
        kvs[(size_t)bh * 4096 + d * 64 + e0 + j] = ss;
    }
    if (tid < 64) {
        float sg = 0.f, ss = 0.f;
#pragma unroll 4
        for (int c = 0; c < 8; c++) {
            sg += pks[(bh * 8 + c) * 128 + tid];
            ss += pks[(bh * 8 + c) * 128 + 64 + tid];
        }
        ksgL[tid] = sg;
        if (eb == 0) ksums[bh * 64 + tid] = ss;
    }
    __syncthreads();
    if (tid < 12) {
        float nrm = 0.f;
        for (int dd = 0; dd < 64; dd++)
            nrm += fmapf(aq[h * 768 + tid * 64 + dd]) * ksgL[dd];
        anorm[tid] = fmaxf(nrm, 1e-6f);
    }
    __syncthreads();
    if (tid < 192) {
        int a = tid >> 4, j = tid & 15;
        float acc = 0.f;
        for (int dd = 0; dd < 64; dd++)
            acc += fmapf(aq[h * 768 + a * 64 + dd]) * kvgL[dd][j];
        aout[(size_t)bh * 768 + a * 64 + e0 + j] = acc / anorm[a];
    }
}

// ---------------------------------------------------------------------------
// Kernel 3: per 64-token tile of one (b,h): local band (window 12; padded
// keys = fmap(0)=1, padded v = 0), stride band (q @ kv_s / q.ksum_s),
// global band (q.aq_f -> weighted anchor_out). Combine with softmax weights,
// write attn in (B,S,768) layout for the final GEMM.
// Grid: (B*H)*32 blocks of 256 threads.  LDS ~63 KB.
// ---------------------------------------------------------------------------
__global__ __launch_bounds__(256) void combine(const float* __restrict__ qf,
                                               const float* __restrict__ kf,
                                               const float* __restrict__ vv,
                                               const float* __restrict__ aq,
                                               const float* __restrict__ kvs,
                                               const float* __restrict__ ksums,
                                               const float* __restrict__ aout,
                                               const float* __restrict__ wlp,
                                               const float* __restrict__ wsp,
                                               const float* __restrict__ wgp,
                                               float* __restrict__ attn) {
    __shared__ float kvsL[64][65];
    __shared__ float qft[64][65];
    __shared__ float kft[75][65];
    __shared__ float aoutL[12][64];
    __shared__ float qkl[64][12];
    __shared__ float qkg[64][12];
    __shared__ float ksumL[64];
    __shared__ float nl[64], ng[64], ns[64];
    int bh = blockIdx.x >> 5, stile = blockIdx.x & 31;
    int b = bh / H_, h = bh % H_;
    int s0 = stile * 64;
    int tid = threadIdx.x;
    const float* qfp = qf + (size_t)bh * S_ * HD;
    const float* kfp = kf + (size_t)bh * S_ * HD;
    const float* vp = vv + (size_t)bh * S_ * HD;
    // softmax of the three scalar weights (redundant per thread, cheap)
    float a0 = wlp[0], a1 = wsp[0], a2 = wgp[0];
    float mx = fmaxf(a0, fmaxf(a1, a2));
    float ew0 = __expf(a0 - mx), ew1 = __expf(a1 - mx), ew2 = __expf(a2 - mx);
    float inv = 1.f / (ew0 + ew1 + ew2);
    float wl = ew0 * inv, wsb = ew1 * inv, wg = ew2 * inv;
    // stage
    for (int i = tid; i < 4096; i += 256) {
        kvsL[i >> 6][i & 63] = kvs[(size_t)bh * 4096 + i];
        qft[i >> 6][i & 63] = qfp[(size_t)s0 * HD + i];
    }
    for (int i = tid; i < 75 * 64; i += 256) {
        int row = i >> 6, c = i & 63;
        int gs = s0 + row - 6;
        kft[row][c] = (gs >= 0 && gs < S_) ? kfp[(size_t)gs * HD + c] : 1.0f;
    }
    if (tid < 64) ksumL[tid] = ksums[bh * 64 + tid];
    for (int i = tid; i < 768; i += 256) aoutL[i >> 6][i & 63] = aout[(size_t)bh * 768 + i];
    __syncthreads();
    // phase A: 64 tokens x (12 local qk + 12 global qk + 1 stride norm)
    for (int r = tid; r < 64 * 25; r += 256) {
        int token = r / 25;
        int which = r - token * 25;
        float acc = 0.f;
        if (which < 12) {
            int row = token + which;
#pragma unroll 8
            for (int dd = 0; dd < 64; dd++) acc += qft[token][dd] * kft[row][dd];
            qkl[token][which] = acc;
        } else if (which < 24) {
            int a = which - 12;
            const float* ap = aq + h * 768 + a * 64;
#pragma unroll 8
            for (int dd = 0; dd < 64; dd++) acc += qft[token][dd] * fmapf(ap[dd]);
            qkg[token][a] = acc;
        } else {
#pragma unroll 8
            for (int dd = 0; dd < 64; dd++) acc += qft[token][dd] * ksumL[dd];
            ns[token] = acc;
        }
    }
    __syncthreads();
    if (tid < 64) {
        float sl = 0.f, sg = 0.f;
#pragma unroll
        for (int j = 0; j < 12; j++) { sl += qkl[tid][j]; sg += qkg[tid][j]; }
        nl[tid] = fmaxf(sl, 1e-6f);
        ng[tid] = fmaxf(sg, 1e-6f);
        ns[tid] = fmaxf(ns[tid], 1e-6f);
    }
    __syncthreads();
    // phase B: each (token,e) output
    int e = tid & 63, tg = tid >> 6;
    for (int token = tg; token < 64; token += 4) {
        float ol = 0.f;
#pragma unroll
        for (int j = 0; j < 12; j++) {
            int gs = s0 + token + j - 6;  // uniform per wave
            float vval = (gs >= 0 && gs < S_) ? vp[(size_t)gs * HD + e] : 0.f;
            ol += qkl[token][j] * vval;
        }
        float os = 0.f;
#pragma unroll 16
        for (int dd = 0; dd < 64; dd++) os += qft[token][dd] * kvsL[dd][e];
        float og = 0.f;
#pragma unroll
        for (int a = 0; a < 12; a++) og += qkg[token][a] * aoutL[a][e];
        float res = wl * ol / nl[token] + wsb * os / ns[token] + wg * og / ng[token];
        attn[((size_t)(b * S_ + s0 + token)) * 768 + h * 64 + e] = res;
    }
}

// ---------------------------------------------------------------------------
// Kernel 4: out = attn @ out_w.T  (8192x768)@(768x768) -> fp32
// ---------------------------------------------------------------------------
__global__ __launch_bounds__(256) void out_gemm(const float* __restrict__ attn,
                                                const float* __restrict__ w,
                                                float* __restrict__ out) {
    __shared__ float As[16][64];
    __shared__ float Bs[16][64];
    const int K = 768;
    int n0 = blockIdx.x * 64, m0 = blockIdx.y * 64;
    int tid = threadIdx.x;
    int tx = tid & 15, ty = tid >> 4;
    float acc[4][4] = {};
    for (int k0 = 0; k0 < K; k0 += 16) {
        int lin = tid * 4;
        int mA = lin >> 4, kA = lin & 15;
        const float* ap = attn + (size_t)(m0 + mA) * K + k0 + kA;
        const float* wp = w + (size_t)(n0 + mA) * K + k0 + kA;
        float4 xa = *(const float4*)ap;
        float4 wa = *(const float4*)wp;
        As[kA + 0][mA] = xa.x; As[kA + 1][mA] = xa.y;
        As[kA + 2][mA] = xa.z; As[kA + 3][mA] = xa.w;
        Bs[kA + 0][mA] = wa.x; Bs[kA + 1][mA] = wa.y;
        Bs[kA + 2][mA] = wa.z; Bs[kA + 3][mA] = wa.w;
        __syncthreads();
#pragma unroll
        for (int kk = 0; kk < 16; kk++) {
            float a_[4], b_[4];
#pragma unroll
            for (int i = 0; i < 4; i++) a_[i] = As[kk][ty * 4 + i];
#pragma unroll
            for (int j = 0; j < 4; j++) b_[j] = Bs[kk][tx * 4 + j];
#pragma unroll
            for (int i = 0; i < 4; i++)
#pragma unroll
                for (int j = 0; j < 4; j++) acc[i][j] += a_[i] * b_[j];
        }
        __syncthreads();
    }
#pragma unroll
    for (int i = 0; i < 4; i++) {
        int m = m0 + ty * 4 + i;
#pragma unroll
        for (int j = 0; j < 4; j++) {
            int n = n0 + tx * 4 + j;
            out[(size_t)m * 768 + n] = acc[i][j];
        }
    }
}

extern "C" void kernel_launch(void* const* d_in, const int* in_sizes, int n_in,
                              void* d_out, int out_size, void* d_ws, size_t ws_size,
                              hipStream_t stream) {
    const float* x = (const float*)d_in[0];
    const float* qkvw = (const float*)d_in[1];
    const float* outw = (const float*)d_in[2];
    const float* aq = (const float*)d_in[3];
    const float* wlp = (const float*)d_in[4];
    const float* wsp = (const float*)d_in[5];
    const float* wgp = (const float*)d_in[6];

    float* ws = (float*)d_ws;
    const size_t NBH = (size_t)B_ * H_ * S_ * HD;  // 6,291,456
    float* qf = ws;
    float* kf = qf + NBH;
    float* vv = kf + NBH;
    float* attn = vv + NBH;              // NBH floats; dead until `combine`
    float* kvs = attn + NBH;             // 48*4096
    float* ksums = kvs + 48 * 4096;      // 48*64
    float* aout = ksums + 48 * 64;       // 48*768
    // pkv/pks packed INSIDE the attn region (3,145,728 + 49,152 < NBH floats)
    float* pkv = attn;                   // 48*8*2*4096 = 3,145,728 floats
    float* pks = attn + (size_t)48 * 8 * 2 * 4096;  // 48*8*128 = 49,152 floats

    qkv_gemm<<<dim3(36, 128), 256, 0, stream>>>(x, qkvw, qf, kf, vv);
    band_partial<<<48 * 8, 256, 0, stream>>>(kf, vv, pkv, pks);
    band_reduce<<<48 * 4, 256, 0, stream>>>(pkv, pks, aq, kvs, ksums, aout);
    combine<<<48 * 32, 256, 0, stream>>>(qf, kf, vv, aq, kvs, ksums, aout, wlp, wsp, wgp, attn);
    out_gemm<<<dim3(12, 128), 256, 0, stream>>>(attn, outw, (float*)d_out);
}

// Round 9
// 562.330 us; speedup vs baseline: 2.3542x; 1.5230x over previous
//
#include <hip/hip_runtime.h>
#include <hip/hip_bf16.h>

#define B_ 4
#define S_ 2048
#define D_ 768
#define H_ 12
#define HD 64

typedef __attribute__((ext_vector_type(8))) short short8;
typedef __attribute__((ext_vector_type(4))) float f32x4;

__device__ __forceinline__ float fmapf(float x) { return x > 0.f ? x + 1.f : __expf(x); }

// fp32 -> bf16 round-to-nearest-even (finite inputs only)
__device__ __forceinline__ short f2bs(float f) {
    unsigned u = __float_as_uint(f);
    u += 0x7FFFu + ((u >> 16) & 1u);
    return (short)(u >> 16);
}

// ---------------------------------------------------------------------------
// Kernel 1: qkv = x @ qkv_w.T via bf16 MFMA (16x16x32), fp32 accumulate.
// M=8192, N=2304, K=768. 128x128 tile, BK=32, 256 thr (4 waves, 64x64 each).
// fp32 inputs converted to bf16 (RNE) during LDS staging. Epilogue applies
// fmap to q,k and scatters into (B,H,S,hd) fp32 buffers.
// ---------------------------------------------------------------------------
__global__ __launch_bounds__(256) void qkv_gemm_mfma(const float* __restrict__ x,
                                                     const float* __restrict__ w,
                                                     float* __restrict__ qf,
                                                     float* __restrict__ kf,
                                                     float* __restrict__ vv) {
    __shared__ short As[128][40];  // 128 x 32 bf16, +8 pad (80B row stride)
    __shared__ short Bs[128][40];
    const int K = 768;
    int n0 = blockIdx.x * 128, m0 = blockIdx.y * 128;
    int tid = threadIdx.x, lane = tid & 63, wave = tid >> 6;
    int wm = (wave & 1) * 64, wn = (wave >> 1) * 64;
    int quad = lane >> 4, l15 = lane & 15;
    int srow = tid >> 1, scol = (tid & 1) * 16;
    f32x4 acc[4][4];
#pragma unroll
    for (int i = 0; i < 4; i++)
#pragma unroll
        for (int j = 0; j < 4; j++) acc[i][j] = 0.f;

    for (int k0 = 0; k0 < K; k0 += 32) {
        const float* xp = x + (size_t)(m0 + srow) * K + k0 + scol;
        const float* wp = w + (size_t)(n0 + srow) * K + k0 + scol;
        float4 x0 = *(const float4*)xp, x1 = *(const float4*)(xp + 4);
        float4 x2 = *(const float4*)(xp + 8), x3 = *(const float4*)(xp + 12);
        float4 w0 = *(const float4*)wp, w1 = *(const float4*)(wp + 4);
        float4 w2 = *(const float4*)(wp + 8), w3 = *(const float4*)(wp + 12);
        short8 alo, ahi, blo, bhi;
        alo[0]=f2bs(x0.x); alo[1]=f2bs(x0.y); alo[2]=f2bs(x0.z); alo[3]=f2bs(x0.w);
        alo[4]=f2bs(x1.x); alo[5]=f2bs(x1.y); alo[6]=f2bs(x1.z); alo[7]=f2bs(x1.w);
        ahi[0]=f2bs(x2.x); ahi[1]=f2bs(x2.y); ahi[2]=f2bs(x2.z); ahi[3]=f2bs(x2.w);
        ahi[4]=f2bs(x3.x); ahi[5]=f2bs(x3.y); ahi[6]=f2bs(x3.z); ahi[7]=f2bs(x3.w);
        blo[0]=f2bs(w0.x); blo[1]=f2bs(w0.y); blo[2]=f2bs(w0.z); blo[3]=f2bs(w0.w);
        blo[4]=f2bs(w1.x); blo[5]=f2bs(w1.y); blo[6]=f2bs(w1.z); blo[7]=f2bs(w1.w);
        bhi[0]=f2bs(w2.x); bhi[1]=f2bs(w2.y); bhi[2]=f2bs(w2.z); bhi[3]=f2bs(w2.w);
        bhi[4]=f2bs(w3.x); bhi[5]=f2bs(w3.y); bhi[6]=f2bs(w3.z); bhi[7]=f2bs(w3.w);
        *(short8*)&As[srow][scol] = alo;
        *(short8*)&As[srow][scol + 8] = ahi;
        *(short8*)&Bs[srow][scol] = blo;
        *(short8*)&Bs[srow][scol + 8] = bhi;
        __syncthreads();
        short8 af[4], bfr[4];
#pragma unroll
        for (int i = 0; i < 4; i++) af[i] = *(short8*)&As[wm + i * 16 + l15][quad * 8];
#pragma unroll
        for (int j = 0; j < 4; j++) bfr[j] = *(short8*)&Bs[wn + j * 16 + l15][quad * 8];
#pragma unroll
        for (int i = 0; i < 4; i++)
#pragma unroll
            for (int j = 0; j < 4; j++)
                acc[i][j] = __builtin_amdgcn_mfma_f32_16x16x32_bf16(af[i], bfr[j], acc[i][j], 0, 0, 0);
        __syncthreads();
    }
#pragma unroll
    for (int j = 0; j < 4; j++) {
        int col = n0 + wn + j * 16 + l15;
        int t3 = col / 768;
        int r = col - t3 * 768;
        int h = r >> 6, d = r & 63;
#pragma unroll
        for (int i = 0; i < 4; i++) {
#pragma unroll
            for (int rr = 0; rr < 4; rr++) {
                int m = m0 + wm + i * 16 + quad * 4 + rr;
                int b = m >> 11, s = m & 2047;
                size_t dst = (((size_t)(b * H_ + h) * S_) + s) * HD + d;
                float val = acc[i][j][rr];
                if (t3 == 0)
                    qf[dst] = fmapf(val);
                else if (t3 == 1)
                    kf[dst] = fmapf(val);
                else
                    vv[dst] = val;
            }
        }
    }
}

// ---------------------------------------------------------------------------
// Kernel 2a: partial kv states. Grid = 48 bh * 8 chunks (256 tokens each).
// ---------------------------------------------------------------------------
__global__ __launch_bounds__(256) void band_partial(const float* __restrict__ kf,
                                                    const float* __restrict__ vv,
                                                    float* __restrict__ pkv,
                                                    float* __restrict__ pks) {
    int bh = blockIdx.x >> 3, chunk = blockIdx.x & 7;
    int sbase = chunk * 256;
    const float* kfp = kf + (size_t)bh * S_ * HD + (size_t)sbase * HD;
    const float* vp = vv + (size_t)bh * S_ * HD + (size_t)sbase * HD;
    __shared__ float kt[16][64];
    __shared__ float vt[16][64];
    int tid = threadIdx.x;
    int d = tid >> 2, eg = tid & 3, e0 = eg * 16;
    float accg[16], accs[16];
#pragma unroll
    for (int i = 0; i < 16; i++) { accg[i] = 0.f; accs[i] = 0.f; }
    float ksg = 0.f, kss = 0.f;
    for (int s0 = 0; s0 < 256; s0 += 16) {
        for (int i = tid; i < 1024; i += 256) {
            kt[i >> 6][i & 63] = kfp[(size_t)s0 * HD + i];
            vt[i >> 6][i & 63] = vp[(size_t)s0 * HD + i];
        }
        __syncthreads();
#pragma unroll 4
        for (int ss = 0; ss < 16; ss++) {
            float kd = kt[ss][d];
            bool str = ((sbase + s0 + ss) % 3) == 0;  // block-uniform
            ksg += kd;
            if (str) kss += kd;
#pragma unroll
            for (int i = 0; i < 16; i++) {
                float ve = vt[ss][e0 + i];
                accg[i] += kd * ve;
                if (str) accs[i] += kd * ve;
            }
        }
        __syncthreads();
    }
    float* pg = pkv + (size_t)blockIdx.x * 2 * 4096;
#pragma unroll
    for (int i = 0; i < 16; i++) pg[d * 64 + e0 + i] = accg[i];
#pragma unroll
    for (int i = 0; i < 16; i++) pg[4096 + d * 64 + e0 + i] = accs[i];
    if (eg == 0) {
        pks[blockIdx.x * 128 + d] = ksg;
        pks[blockIdx.x * 128 + 64 + d] = kss;
    }
}

// ---------------------------------------------------------------------------
// Kernel 2b: reduce partials + anchor outputs. Grid = 48 bh * 4 e-blocks.
// ---------------------------------------------------------------------------
__global__ __launch_bounds__(256) void band_reduce(const float* __restrict__ pkv,
                                                   const float* __restrict__ pks,
                                                   const float* __restrict__ aq,
                                                   float* __restrict__ kvs,
                                                   float* __restrict__ ksums,
                                                   float* __restrict__ aout) {
    int bh = blockIdx.x >> 2, eb = blockIdx.x & 3, e0 = eb * 16;
    int h = bh % H_;
    __shared__ float kvgL[64][17];
    __shared__ float ksgL[64];
    __shared__ float anorm[12];
    int tid = threadIdx.x;
    for (int idx = tid; idx < 1024; idx += 256) {
        int d = idx >> 4, j = idx & 15;
        float sg = 0.f, ss = 0.f;
        const float* p = pkv + (size_t)(bh * 8) * 2 * 4096 + d * 64 + e0 + j;
#pragma unroll 4
        for (int c = 0; c < 8; c++) {
            sg += p[0];
            ss += p[4096];
            p += 2 * 4096;
        }
        kvgL[d][j] = sg;
        kvs[(size_t)bh * 4096 + d * 64 + e0 + j] = ss;
    }
    if (tid < 64) {
        float sg = 0.f, ss = 0.f;
#pragma unroll 4
        for (int c = 0; c < 8; c++) {
            sg += pks[(bh * 8 + c) * 128 + tid];
            ss += pks[(bh * 8 + c) * 128 + 64 + tid];
        }
        ksgL[tid] = sg;
        if (eb == 0) ksums[bh * 64 + tid] = ss;
    }
    __syncthreads();
    if (tid < 12) {
        float nrm = 0.f;
        for (int dd = 0; dd < 64; dd++)
            nrm += fmapf(aq[h * 768 + tid * 64 + dd]) * ksgL[dd];
        anorm[tid] = fmaxf(nrm, 1e-6f);
    }
    __syncthreads();
    if (tid < 192) {
        int a = tid >> 4, j = tid & 15;
        float acc = 0.f;
        for (int dd = 0; dd < 64; dd++)
            acc += fmapf(aq[h * 768 + a * 64 + dd]) * kvgL[dd][j];
        aout[(size_t)bh * 768 + a * 64 + e0 + j] = acc / anorm[a];
    }
}

// ---------------------------------------------------------------------------
// Kernel 3: combine the three bands; write attn (fp32) in (B,S,768).
// ---------------------------------------------------------------------------
__global__ __launch_bounds__(256) void combine(const float* __restrict__ qf,
                                               const float* __restrict__ kf,
                                               const float* __restrict__ vv,
                                               const float* __restrict__ aq,
                                               const float* __restrict__ kvs,
                                               const float* __restrict__ ksums,
                                               const float* __restrict__ aout,
                                               const float* __restrict__ wlp,
                                               const float* __restrict__ wsp,
                                               const float* __restrict__ wgp,
                                               float* __restrict__ attn) {
    __shared__ float kvsL[64][65];
    __shared__ float qft[64][65];
    __shared__ float kft[75][65];
    __shared__ float aoutL[12][64];
    __shared__ float qkl[64][12];
    __shared__ float qkg[64][12];
    __shared__ float ksumL[64];
    __shared__ float nl[64], ng[64], ns[64];
    int bh = blockIdx.x >> 5, stile = blockIdx.x & 31;
    int b = bh / H_, h = bh % H_;
    int s0 = stile * 64;
    int tid = threadIdx.x;
    const float* qfp = qf + (size_t)bh * S_ * HD;
    const float* kfp = kf + (size_t)bh * S_ * HD;
    const float* vp = vv + (size_t)bh * S_ * HD;
    float a0 = wlp[0], a1 = wsp[0], a2 = wgp[0];
    float mx = fmaxf(a0, fmaxf(a1, a2));
    float ew0 = __expf(a0 - mx), ew1 = __expf(a1 - mx), ew2 = __expf(a2 - mx);
    float inv = 1.f / (ew0 + ew1 + ew2);
    float wl = ew0 * inv, wsb = ew1 * inv, wg = ew2 * inv;
    for (int i = tid; i < 4096; i += 256) {
        kvsL[i >> 6][i & 63] = kvs[(size_t)bh * 4096 + i];
        qft[i >> 6][i & 63] = qfp[(size_t)s0 * HD + i];
    }
    for (int i = tid; i < 75 * 64; i += 256) {
        int row = i >> 6, c = i & 63;
        int gs = s0 + row - 6;
        kft[row][c] = (gs >= 0 && gs < S_) ? kfp[(size_t)gs * HD + c] : 1.0f;
    }
    if (tid < 64) ksumL[tid] = ksums[bh * 64 + tid];
    for (int i = tid; i < 768; i += 256) aoutL[i >> 6][i & 63] = aout[(size_t)bh * 768 + i];
    __syncthreads();
    for (int r = tid; r < 64 * 25; r += 256) {
        int token = r / 25;
        int which = r - token * 25;
        float acc = 0.f;
        if (which < 12) {
            int row = token + which;
#pragma unroll 8
            for (int dd = 0; dd < 64; dd++) acc += qft[token][dd] * kft[row][dd];
            qkl[token][which] = acc;
        } else if (which < 24) {
            int a = which - 12;
            const float* ap = aq + h * 768 + a * 64;
#pragma unroll 8
            for (int dd = 0; dd < 64; dd++) acc += qft[token][dd] * fmapf(ap[dd]);
            qkg[token][a] = acc;
        } else {
#pragma unroll 8
            for (int dd = 0; dd < 64; dd++) acc += qft[token][dd] * ksumL[dd];
            ns[token] = acc;
        }
    }
    __syncthreads();
    if (tid < 64) {
        float sl = 0.f, sg = 0.f;
#pragma unroll
        for (int j = 0; j < 12; j++) { sl += qkl[tid][j]; sg += qkg[tid][j]; }
        nl[tid] = fmaxf(sl, 1e-6f);
        ng[tid] = fmaxf(sg, 1e-6f);
        ns[tid] = fmaxf(ns[tid], 1e-6f);
    }
    __syncthreads();
    int e = tid & 63, tg = tid >> 6;
    for (int token = tg; token < 64; token += 4) {
        float ol = 0.f;
#pragma unroll
        for (int j = 0; j < 12; j++) {
            int gs = s0 + token + j - 6;  // uniform per wave
            float vval = (gs >= 0 && gs < S_) ? vp[(size_t)gs * HD + e] : 0.f;
            ol += qkl[token][j] * vval;
        }
        float os = 0.f;
#pragma unroll 16
        for (int dd = 0; dd < 64; dd++) os += qft[token][dd] * kvsL[dd][e];
        float og = 0.f;
#pragma unroll
        for (int a = 0; a < 12; a++) og += qkg[token][a] * aoutL[a][e];
        float res = wl * ol / nl[token] + wsb * os / ns[token] + wg * og / ng[token];
        attn[((size_t)(b * S_ + s0 + token)) * 768 + h * 64 + e] = res;
    }
}

// ---------------------------------------------------------------------------
// Kernel 4: out = attn @ out_w.T  (8192x768)@(768x768) -> fp32 (round-5 ver.)
// ---------------------------------------------------------------------------
__global__ __launch_bounds__(256) void out_gemm(const float* __restrict__ attn,
                                                const float* __restrict__ w,
                                                float* __restrict__ out) {
    __shared__ float As[16][64];
    __shared__ float Bs[16][64];
    const int K = 768;
    int n0 = blockIdx.x * 64, m0 = blockIdx.y * 64;
    int tid = threadIdx.x;
    int tx = tid & 15, ty = tid >> 4;
    float acc[4][4] = {};
    for (int k0 = 0; k0 < K; k0 += 16) {
        int lin = tid * 4;
        int mA = lin >> 4, kA = lin & 15;
        const float* ap = attn + (size_t)(m0 + mA) * K + k0 + kA;
        const float* wp = w + (size_t)(n0 + mA) * K + k0 + kA;
        float4 xa = *(const float4*)ap;
        float4 wa = *(const float4*)wp;
        As[kA + 0][mA] = xa.x; As[kA + 1][mA] = xa.y;
        As[kA + 2][mA] = xa.z; As[kA + 3][mA] = xa.w;
        Bs[kA + 0][mA] = wa.x; Bs[kA + 1][mA] = wa.y;
        Bs[kA + 2][mA] = wa.z; Bs[kA + 3][mA] = wa.w;
        __syncthreads();
#pragma unroll
        for (int kk = 0; kk < 16; kk++) {
            float a_[4], b_[4];
#pragma unroll
            for (int i = 0; i < 4; i++) a_[i] = As[kk][ty * 4 + i];
#pragma unroll
            for (int j = 0; j < 4; j++) b_[j] = Bs[kk][tx * 4 + j];
#pragma unroll
            for (int i = 0; i < 4; i++)
#pragma unroll
                for (int j = 0; j < 4; j++) acc[i][j] += a_[i] * b_[j];
        }
        __syncthreads();
    }
#pragma unroll
    for (int i = 0; i < 4; i++) {
        int m = m0 + ty * 4 + i;
#pragma unroll
        for (int j = 0; j < 4; j++) {
            int n = n0 + tx * 4 + j;
            out[(size_t)m * 768 + n] = acc[i][j];
        }
    }
}

extern "C" void kernel_launch(void* const* d_in, const int* in_sizes, int n_in,
                              void* d_out, int out_size, void* d_ws, size_t ws_size,
                              hipStream_t stream) {
    const float* x = (const float*)d_in[0];
    const float* qkvw = (const float*)d_in[1];
    const float* outw = (const float*)d_in[2];
    const float* aq = (const float*)d_in[3];
    const float* wlp = (const float*)d_in[4];
    const float* wsp = (const float*)d_in[5];
    const float* wgp = (const float*)d_in[6];

    float* ws = (float*)d_ws;
    const size_t NBH = (size_t)B_ * H_ * S_ * HD;  // 6,291,456
    float* qf = ws;
    float* kf = qf + NBH;
    float* vv = kf + NBH;
    float* attn = vv + NBH;              // NBH floats; dead until `combine`
    float* kvs = attn + NBH;             // 48*4096
    float* ksums = kvs + 48 * 4096;      // 48*64
    float* aout = ksums + 48 * 64;       // 48*768
    // pkv/pks packed INSIDE the attn region (dead until combine writes it)
    float* pkv = attn;                   // 48*8*2*4096 = 3,145,728 floats
    float* pks = attn + (size_t)48 * 8 * 2 * 4096;  // 49,152 floats

    qkv_gemm_mfma<<<dim3(18, 64), 256, 0, stream>>>(x, qkvw, qf, kf, vv);
    band_partial<<<48 * 8, 256, 0, stream>>>(kf, vv, pkv, pks);
    band_reduce<<<48 * 4, 256, 0, stream>>>(pkv, pks, aq, kvs, ksums, aout);
    combine<<<48 * 32, 256, 0, stream>>>(qf, kf, vv, aq, kvs, ksums, aout, wlp, wsp, wgp, attn);
    out_gemm<<<dim3(12, 128), 256, 0, stream>>>(attn, outw, (float*)d_out);
}

// Round 10
// 437.180 us; speedup vs baseline: 3.0281x; 1.2863x over previous
//
#include <hip/hip_runtime.h>
#include <hip/hip_bf16.h>

#define B_ 4
#define S_ 2048
#define D_ 768
#define H_ 12
#define HD 64

typedef __attribute__((ext_vector_type(8))) short short8;
typedef __attribute__((ext_vector_type(4))) float f32x4;

__device__ __forceinline__ float fmapf(float x) { return x > 0.f ? x + 1.f : __expf(x); }

// fp32 -> bf16 round-to-nearest-even (finite inputs only)
__device__ __forceinline__ short f2bs(float f) {
    unsigned u = __float_as_uint(f);
    u += 0x7FFFu + ((u >> 16) & 1u);
    return (short)(u >> 16);
}
__device__ __forceinline__ unsigned short f2bu(float f) {
    unsigned u = __float_as_uint(f);
    u += 0x7FFFu + ((u >> 16) & 1u);
    return (unsigned short)(u >> 16);
}
__device__ __forceinline__ float bu2f(unsigned short v) {
    return __uint_as_float((unsigned)v << 16);
}

// ---------------------------------------------------------------------------
// Kernel 1: qkv = x @ qkv_w.T via bf16 MFMA (16x16x32), fp32 accumulate.
// M=8192, N=2304, K=768. 128x128 tile, BK=32, 256 thr (4 waves, 64x64 each).
// ---------------------------------------------------------------------------
__global__ __launch_bounds__(256) void qkv_gemm_mfma(const float* __restrict__ x,
                                                     const float* __restrict__ w,
                                                     float* __restrict__ qf,
                                                     float* __restrict__ kf,
                                                     float* __restrict__ vv) {
    __shared__ short As[128][40];  // 128 x 32 bf16, +8 pad (80B row stride)
    __shared__ short Bs[128][40];
    const int K = 768;
    int n0 = blockIdx.x * 128, m0 = blockIdx.y * 128;
    int tid = threadIdx.x, lane = tid & 63, wave = tid >> 6;
    int wm = (wave & 1) * 64, wn = (wave >> 1) * 64;
    int quad = lane >> 4, l15 = lane & 15;
    int srow = tid >> 1, scol = (tid & 1) * 16;
    f32x4 acc[4][4];
#pragma unroll
    for (int i = 0; i < 4; i++)
#pragma unroll
        for (int j = 0; j < 4; j++) acc[i][j] = 0.f;

    for (int k0 = 0; k0 < K; k0 += 32) {
        const float* xp = x + (size_t)(m0 + srow) * K + k0 + scol;
        const float* wp = w + (size_t)(n0 + srow) * K + k0 + scol;
        float4 x0 = *(const float4*)xp, x1 = *(const float4*)(xp + 4);
        float4 x2 = *(const float4*)(xp + 8), x3 = *(const float4*)(xp + 12);
        float4 w0 = *(const float4*)wp, w1 = *(const float4*)(wp + 4);
        float4 w2 = *(const float4*)(wp + 8), w3 = *(const float4*)(wp + 12);
        short8 alo, ahi, blo, bhi;
        alo[0]=f2bs(x0.x); alo[1]=f2bs(x0.y); alo[2]=f2bs(x0.z); alo[3]=f2bs(x0.w);
        alo[4]=f2bs(x1.x); alo[5]=f2bs(x1.y); alo[6]=f2bs(x1.z); alo[7]=f2bs(x1.w);
        ahi[0]=f2bs(x2.x); ahi[1]=f2bs(x2.y); ahi[2]=f2bs(x2.z); ahi[3]=f2bs(x2.w);
        ahi[4]=f2bs(x3.x); ahi[5]=f2bs(x3.y); ahi[6]=f2bs(x3.z); ahi[7]=f2bs(x3.w);
        blo[0]=f2bs(w0.x); blo[1]=f2bs(w0.y); blo[2]=f2bs(w0.z); blo[3]=f2bs(w0.w);
        blo[4]=f2bs(w1.x); blo[5]=f2bs(w1.y); blo[6]=f2bs(w1.z); blo[7]=f2bs(w1.w);
        bhi[0]=f2bs(w2.x); bhi[1]=f2bs(w2.y); bhi[2]=f2bs(w2.z); bhi[3]=f2bs(w2.w);
        bhi[4]=f2bs(w3.x); bhi[5]=f2bs(w3.y); bhi[6]=f2bs(w3.z); bhi[7]=f2bs(w3.w);
        *(short8*)&As[srow][scol] = alo;
        *(short8*)&As[srow][scol + 8] = ahi;
        *(short8*)&Bs[srow][scol] = blo;
        *(short8*)&Bs[srow][scol + 8] = bhi;
        __syncthreads();
        short8 af[4], bfr[4];
#pragma unroll
        for (int i = 0; i < 4; i++) af[i] = *(short8*)&As[wm + i * 16 + l15][quad * 8];
#pragma unroll
        for (int j = 0; j < 4; j++) bfr[j] = *(short8*)&Bs[wn + j * 16 + l15][quad * 8];
#pragma unroll
        for (int i = 0; i < 4; i++)
#pragma unroll
            for (int j = 0; j < 4; j++)
                acc[i][j] = __builtin_amdgcn_mfma_f32_16x16x32_bf16(af[i], bfr[j], acc[i][j], 0, 0, 0);
        __syncthreads();
    }
#pragma unroll
    for (int j = 0; j < 4; j++) {
        int col = n0 + wn + j * 16 + l15;
        int t3 = col / 768;
        int r = col - t3 * 768;
        int h = r >> 6, d = r & 63;
#pragma unroll
        for (int i = 0; i < 4; i++) {
#pragma unroll
            for (int rr = 0; rr < 4; rr++) {
                int m = m0 + wm + i * 16 + quad * 4 + rr;
                int b = m >> 11, s = m & 2047;
                size_t dst = (((size_t)(b * H_ + h) * S_) + s) * HD + d;
                float val = acc[i][j][rr];
                if (t3 == 0)
                    qf[dst] = fmapf(val);
                else if (t3 == 1)
                    kf[dst] = fmapf(val);
                else
                    vv[dst] = val;
            }
        }
    }
}

// ---------------------------------------------------------------------------
// Kernel 2a: partial kv states. Grid = 48 bh * 8 chunks (256 tokens each).
// ---------------------------------------------------------------------------
__global__ __launch_bounds__(256) void band_partial(const float* __restrict__ kf,
                                                    const float* __restrict__ vv,
                                                    float* __restrict__ pkv,
                                                    float* __restrict__ pks) {
    int bh = blockIdx.x >> 3, chunk = blockIdx.x & 7;
    int sbase = chunk * 256;
    const float* kfp = kf + (size_t)bh * S_ * HD + (size_t)sbase * HD;
    const float* vp = vv + (size_t)bh * S_ * HD + (size_t)sbase * HD;
    __shared__ float kt[16][64];
    __shared__ float vt[16][64];
    int tid = threadIdx.x;
    int d = tid >> 2, eg = tid & 3, e0 = eg * 16;
    float accg[16], accs[16];
#pragma unroll
    for (int i = 0; i < 16; i++) { accg[i] = 0.f; accs[i] = 0.f; }
    float ksg = 0.f, kss = 0.f;
    for (int s0 = 0; s0 < 256; s0 += 16) {
        for (int i = tid; i < 1024; i += 256) {
            kt[i >> 6][i & 63] = kfp[(size_t)s0 * HD + i];
            vt[i >> 6][i & 63] = vp[(size_t)s0 * HD + i];
        }
        __syncthreads();
#pragma unroll 4
        for (int ss = 0; ss < 16; ss++) {
            float kd = kt[ss][d];
            bool str = ((sbase + s0 + ss) % 3) == 0;  // block-uniform
            ksg += kd;
            if (str) kss += kd;
#pragma unroll
            for (int i = 0; i < 16; i++) {
                float ve = vt[ss][e0 + i];
                accg[i] += kd * ve;
                if (str) accs[i] += kd * ve;
            }
        }
        __syncthreads();
    }
    float* pg = pkv + (size_t)blockIdx.x * 2 * 4096;
#pragma unroll
    for (int i = 0; i < 16; i++) pg[d * 64 + e0 + i] = accg[i];
#pragma unroll
    for (int i = 0; i < 16; i++) pg[4096 + d * 64 + e0 + i] = accs[i];
    if (eg == 0) {
        pks[blockIdx.x * 128 + d] = ksg;
        pks[blockIdx.x * 128 + 64 + d] = kss;
    }
}

// ---------------------------------------------------------------------------
// Kernel 2b: reduce partials + anchor outputs. Grid = 48 bh * 4 e-blocks.
// ---------------------------------------------------------------------------
__global__ __launch_bounds__(256) void band_reduce(const float* __restrict__ pkv,
                                                   const float* __restrict__ pks,
                                                   const float* __restrict__ aq,
                                                   float* __restrict__ kvs,
                                                   float* __restrict__ ksums,
                                                   float* __restrict__ aout) {
    int bh = blockIdx.x >> 2, eb = blockIdx.x & 3, e0 = eb * 16;
    int h = bh % H_;
    __shared__ float kvgL[64][17];
    __shared__ float ksgL[64];
    __shared__ float anorm[12];
    int tid = threadIdx.x;
    for (int idx = tid; idx < 1024; idx += 256) {
        int d = idx >> 4, j = idx & 15;
        float sg = 0.f, ss = 0.f;
        const float* p = pkv + (size_t)(bh * 8) * 2 * 4096 + d * 64 + e0 + j;
#pragma unroll 4
        for (int c = 0; c < 8; c++) {
            sg += p[0];
            ss += p[4096];
            p += 2 * 4096;
        }
        kvgL[d][j] = sg;
        kvs[(size_t)bh * 4096 + d * 64 + e0 + j] = ss;
    }
    if (tid < 64) {
        float sg = 0.f, ss = 0.f;
#pragma unroll 4
        for (int c = 0; c < 8; c++) {
            sg += pks[(bh * 8 + c) * 128 + tid];
            ss += pks[(bh * 8 + c) * 128 + 64 + tid];
        }
        ksgL[tid] = sg;
        if (eb == 0) ksums[bh * 64 + tid] = ss;
    }
    __syncthreads();
    if (tid < 12) {
        float nrm = 0.f;
        for (int dd = 0; dd < 64; dd++)
            nrm += fmapf(aq[h * 768 + tid * 64 + dd]) * ksgL[dd];
        anorm[tid] = fmaxf(nrm, 1e-6f);
    }
    __syncthreads();
    if (tid < 192) {
        int a = tid >> 4, j = tid & 15;
        float acc = 0.f;
        for (int dd = 0; dd < 64; dd++)
            acc += fmapf(aq[h * 768 + a * 64 + dd]) * kvgL[dd][j];
        aout[(size_t)bh * 768 + a * 64 + e0 + j] = acc / anorm[a];
    }
}

// ---------------------------------------------------------------------------
// Kernel 3: combine the three bands; write attn (fp32) in (B,S,768).
// kft tile stored bf16 to cut LDS 62->53 KB (2 -> 3 blocks/CU occupancy).
// ---------------------------------------------------------------------------
__global__ __launch_bounds__(256) void combine(const float* __restrict__ qf,
                                               const float* __restrict__ kf,
                                               const float* __restrict__ vv,
                                               const float* __restrict__ aq,
                                               const float* __restrict__ kvs,
                                               const float* __restrict__ ksums,
                                               const float* __restrict__ aout,
                                               const float* __restrict__ wlp,
                                               const float* __restrict__ wsp,
                                               const float* __restrict__ wgp,
                                               float* __restrict__ attn) {
    __shared__ float kvsL[64][65];
    __shared__ float qft[64][65];
    __shared__ unsigned short kftb[75][66];  // bf16 local-key tile
    __shared__ float aoutL[12][64];
    __shared__ float qkl[64][12];
    __shared__ float qkg[64][12];
    __shared__ float ksumL[64];
    __shared__ float nl[64], ng[64], ns[64];
    int bh = blockIdx.x >> 5, stile = blockIdx.x & 31;
    int b = bh / H_, h = bh % H_;
    int s0 = stile * 64;
    int tid = threadIdx.x;
    const float* qfp = qf + (size_t)bh * S_ * HD;
    const float* kfp = kf + (size_t)bh * S_ * HD;
    const float* vp = vv + (size_t)bh * S_ * HD;
    float a0 = wlp[0], a1 = wsp[0], a2 = wgp[0];
    float mx = fmaxf(a0, fmaxf(a1, a2));
    float ew0 = __expf(a0 - mx), ew1 = __expf(a1 - mx), ew2 = __expf(a2 - mx);
    float inv = 1.f / (ew0 + ew1 + ew2);
    float wl = ew0 * inv, wsb = ew1 * inv, wg = ew2 * inv;
    for (int i = tid; i < 4096; i += 256) {
        kvsL[i >> 6][i & 63] = kvs[(size_t)bh * 4096 + i];
        qft[i >> 6][i & 63] = qfp[(size_t)s0 * HD + i];
    }
    for (int i = tid; i < 75 * 64; i += 256) {
        int row = i >> 6, c = i & 63;
        int gs = s0 + row - 6;
        float kv_ = (gs >= 0 && gs < S_) ? kfp[(size_t)gs * HD + c] : 1.0f;
        kftb[row][c] = f2bu(kv_);
    }
    if (tid < 64) ksumL[tid] = ksums[bh * 64 + tid];
    for (int i = tid; i < 768; i += 256) aoutL[i >> 6][i & 63] = aout[(size_t)bh * 768 + i];
    __syncthreads();
    for (int r = tid; r < 64 * 25; r += 256) {
        int token = r / 25;
        int which = r - token * 25;
        float acc = 0.f;
        if (which < 12) {
            int row = token + which;
#pragma unroll 8
            for (int dd = 0; dd < 64; dd++) acc += qft[token][dd] * bu2f(kftb[row][dd]);
            qkl[token][which] = acc;
        } else if (which < 24) {
            int a = which - 12;
            const float* ap = aq + h * 768 + a * 64;
#pragma unroll 8
            for (int dd = 0; dd < 64; dd++) acc += qft[token][dd] * fmapf(ap[dd]);
            qkg[token][a] = acc;
        } else {
#pragma unroll 8
            for (int dd = 0; dd < 64; dd++) acc += qft[token][dd] * ksumL[dd];
            ns[token] = acc;
        }
    }
    __syncthreads();
    if (tid < 64) {
        float sl = 0.f, sg = 0.f;
#pragma unroll
        for (int j = 0; j < 12; j++) { sl += qkl[tid][j]; sg += qkg[tid][j]; }
        nl[tid] = fmaxf(sl, 1e-6f);
        ng[tid] = fmaxf(sg, 1e-6f);
        ns[tid] = fmaxf(ns[tid], 1e-6f);
    }
    __syncthreads();
    int e = tid & 63, tg = tid >> 6;
    for (int token = tg; token < 64; token += 4) {
        float ol = 0.f;
#pragma unroll
        for (int j = 0; j < 12; j++) {
            int gs = s0 + token + j - 6;  // uniform per wave
            float vval = (gs >= 0 && gs < S_) ? vp[(size_t)gs * HD + e] : 0.f;
            ol += qkl[token][j] * vval;
        }
        float os = 0.f;
#pragma unroll 16
        for (int dd = 0; dd < 64; dd++) os += qft[token][dd] * kvsL[dd][e];
        float og = 0.f;
#pragma unroll
        for (int a = 0; a < 12; a++) og += qkg[token][a] * aoutL[a][e];
        float res = wl * ol / nl[token] + wsb * os / ns[token] + wg * og / ng[token];
        attn[((size_t)(b * S_ + s0 + token)) * 768 + h * 64 + e] = res;
    }
}

// ---------------------------------------------------------------------------
// Kernel 4: out = attn @ out_w.T via bf16 MFMA, fp32 accumulate.
// M=8192, N=768, K=768. Same proven structure as kernel 1 (fp32 inputs
// converted in staging), plain fp32 epilogue.
// ---------------------------------------------------------------------------
__global__ __launch_bounds__(256) void out_gemm_mfma(const float* __restrict__ attn,
                                                     const float* __restrict__ w,
                                                     float* __restrict__ out) {
    __shared__ short As[128][40];
    __shared__ short Bs[128][40];
    const int K = 768;
    int n0 = blockIdx.x * 128, m0 = blockIdx.y * 128;
    int tid = threadIdx.x, lane = tid & 63, wave = tid >> 6;
    int wm = (wave & 1) * 64, wn = (wave >> 1) * 64;
    int quad = lane >> 4, l15 = lane & 15;
    int srow = tid >> 1, scol = (tid & 1) * 16;
    f32x4 acc[4][4];
#pragma unroll
    for (int i = 0; i < 4; i++)
#pragma unroll
        for (int j = 0; j < 4; j++) acc[i][j] = 0.f;

    for (int k0 = 0; k0 < K; k0 += 32) {
        const float* xp = attn + (size_t)(m0 + srow) * K + k0 + scol;
        const float* wp = w + (size_t)(n0 + srow) * K + k0 + scol;
        float4 x0 = *(const float4*)xp, x1 = *(const float4*)(xp + 4);
        float4 x2 = *(const float4*)(xp + 8), x3 = *(const float4*)(xp + 12);
        float4 w0 = *(const float4*)wp, w1 = *(const float4*)(wp + 4);
        float4 w2 = *(const float4*)(wp + 8), w3 = *(const float4*)(wp + 12);
        short8 alo, ahi, blo, bhi;
        alo[0]=f2bs(x0.x); alo[1]=f2bs(x0.y); alo[2]=f2bs(x0.z); alo[3]=f2bs(x0.w);
        alo[4]=f2bs(x1.x); alo[5]=f2bs(x1.y); alo[6]=f2bs(x1.z); alo[7]=f2bs(x1.w);
        ahi[0]=f2bs(x2.x); ahi[1]=f2bs(x2.y); ahi[2]=f2bs(x2.z); ahi[3]=f2bs(x2.w);
        ahi[4]=f2bs(x3.x); ahi[5]=f2bs(x3.y); ahi[6]=f2bs(x3.z); ahi[7]=f2bs(x3.w);
        blo[0]=f2bs(w0.x); blo[1]=f2bs(w0.y); blo[2]=f2bs(w0.z); blo[3]=f2bs(w0.w);
        blo[4]=f2bs(w1.x); blo[5]=f2bs(w1.y); blo[6]=f2bs(w1.z); blo[7]=f2bs(w1.w);
        bhi[0]=f2bs(w2.x); bhi[1]=f2bs(w2.y); bhi[2]=f2bs(w2.z); bhi[3]=f2bs(w2.w);
        bhi[4]=f2bs(w3.x); bhi[5]=f2bs(w3.y); bhi[6]=f2bs(w3.z); bhi[7]=f2bs(w3.w);
        *(short8*)&As[srow][scol] = alo;
        *(short8*)&As[srow][scol + 8] = ahi;
        *(short8*)&Bs[srow][scol] = blo;
        *(short8*)&Bs[srow][scol + 8] = bhi;
        __syncthreads();
        short8 af[4], bfr[4];
#pragma unroll
        for (int i = 0; i < 4; i++) af[i] = *(short8*)&As[wm + i * 16 + l15][quad * 8];
#pragma unroll
        for (int j = 0; j < 4; j++) bfr[j] = *(short8*)&Bs[wn + j * 16 + l15][quad * 8];
#pragma unroll
        for (int i = 0; i < 4; i++)
#pragma unroll
            for (int j = 0; j < 4; j++)
                acc[i][j] = __builtin_amdgcn_mfma_f32_16x16x32_bf16(af[i], bfr[j], acc[i][j], 0, 0, 0);
        __syncthreads();
    }
#pragma unroll
    for (int j = 0; j < 4; j++) {
        int col = n0 + wn + j * 16 + l15;
#pragma unroll
        for (int i = 0; i < 4; i++) {
#pragma unroll
            for (int rr = 0; rr < 4; rr++) {
                int m = m0 + wm + i * 16 + quad * 4 + rr;
                out[(size_t)m * 768 + col] = acc[i][j][rr];
            }
        }
    }
}

extern "C" void kernel_launch(void* const* d_in, const int* in_sizes, int n_in,
                              void* d_out, int out_size, void* d_ws, size_t ws_size,
                              hipStream_t stream) {
    const float* x = (const float*)d_in[0];
    const float* qkvw = (const float*)d_in[1];
    const float* outw = (const float*)d_in[2];
    const float* aq = (const float*)d_in[3];
    const float* wlp = (const float*)d_in[4];
    const float* wsp = (const float*)d_in[5];
    const float* wgp = (const float*)d_in[6];

    float* ws = (float*)d_ws;
    const size_t NBH = (size_t)B_ * H_ * S_ * HD;  // 6,291,456
    float* qf = ws;
    float* kf = qf + NBH;
    float* vv = kf + NBH;
    float* attn = vv + NBH;              // NBH floats; dead until `combine`
    float* kvs = attn + NBH;             // 48*4096
    float* ksums = kvs + 48 * 4096;      // 48*64
    float* aout = ksums + 48 * 64;       // 48*768
    // pkv/pks packed INSIDE the attn region (dead until combine writes it)
    float* pkv = attn;                   // 48*8*2*4096 = 3,145,728 floats
    float* pks = attn + (size_t)48 * 8 * 2 * 4096;  // 49,152 floats

    qkv_gemm_mfma<<<dim3(18, 64), 256, 0, stream>>>(x, qkvw, qf, kf, vv);
    band_partial<<<48 * 8, 256, 0, stream>>>(kf, vv, pkv, pks);
    band_reduce<<<48 * 4, 256, 0, stream>>>(pkv, pks, aq, kvs, ksums, aout);
    combine<<<48 * 32, 256, 0, stream>>>(qf, kf, vv, aq, kvs, ksums, aout, wlp, wsp, wgp, attn);
    out_gemm_mfma<<<dim3(6, 64), 256, 0, stream>>>(attn, outw, (float*)d_out);
}